// Round 18
// baseline (183.415 us; speedup 1.0000x reference)
//
#include <hip/hip_runtime.h>
#include <hip/hip_bf16.h>

// Problem constants
#define Bz 8
#define Tn 64
#define Mn 500
#define KC 16
#define HA 64
#define HR 64
#define NHID 32
#define DF 160
#define FINALC 512
#define GSPLIT 8
#define STR 512            // padded row stride (halfwords) for Mn-inner fp16 mats

typedef float in_t;   // reference dtypes are all float32
typedef __attribute__((ext_vector_type(8))) _Float16 half8;
typedef __attribute__((ext_vector_type(2))) _Float16 h2v;
typedef __attribute__((ext_vector_type(4))) float f32x4;
typedef __attribute__((ext_vector_type(4))) unsigned int u32x4;
#define MFMAH __builtin_amdgcn_mfma_f32_16x16x32_f16

__device__ __forceinline__ float sigm(float x){ return 1.0f/(1.0f+__expf(-x)); }
__device__ __forceinline__ float tanhfast(float x){ float e=__expf(2.0f*x); return 1.0f-2.0f/(e+1.0f); }
__device__ __forceinline__ float eluf(float x){ return x>0.0f? x : (__expf(x)-1.0f); }
__device__ __forceinline__ unsigned short f2h(float f){
  _Float16 h = (_Float16)f;
  return *reinterpret_cast<unsigned short*>(&h);
}
__device__ __forceinline__ float h2f(unsigned short u){
  _Float16 h = *reinterpret_cast<_Float16*>(&u);
  return (float)h;
}
__device__ __forceinline__ unsigned int pack2h(float a, float b){
  return (unsigned int)f2h(a) | ((unsigned int)f2h(b) << 16);
}

// ---------------------------------------------------------------------------
// K0: fused prep — blocks [0,64) WbT transpose; [64,304) gnnT; [304,424) zpad
__global__ __launch_bounds__(256) void k_prep(
    const in_t* __restrict__ Wb, unsigned short* __restrict__ WbT,
    const in_t* __restrict__ gw, unsigned short* __restrict__ gnnT,
    unsigned short* __restrict__ f0T, unsigned short* __restrict__ f1T)
{
  int blk = blockIdx.x;
  int tid = threadIdx.x;
  if (blk < 64) {
    __shared__ unsigned short ts[64][72];
    int k0 = (blk >> 3)*64, j0 = (blk & 7)*64;
    for (int idx = tid; idx < 4096; idx += 256) {
      int r = idx >> 6, c = idx & 63;
      int k = k0 + r, j = j0 + c;
      ts[r][c] = (k < Mn && j < Mn) ? f2h(Wb[(size_t)k*Mn + j]) : (unsigned short)0;
    }
    __syncthreads();
    for (int idx = tid; idx < 4096; idx += 256) {
      int jr = idx >> 6, kc = idx & 63;
      int j = j0 + jr, k = k0 + kc;
      if (j < Mn) WbT[(size_t)j*STR + k] = ts[kc][jr];
    }
  } else if (blk < 304) {
    int idx = (blk - 64)*256 + tid;     // 61440 = 2*160*192 exact
    int l = idx / (DF*192);
    int rem = idx - l*(DF*192);
    int j = rem / 192, k = rem - j*192;
    gnnT[((size_t)l*DF + j)*192 + k] =
        (k < DF) ? f2h(gw[(size_t)l*DF*DF + (size_t)k*DF + j]) : (unsigned short)0;
  } else {
    int idx = (blk - 304)*256 + tid;    // 30720 = 2*8*160*12 exact
    int buf = idx / (Bz*DF*12);
    int rem = idx - buf*(Bz*DF*12);
    int row = rem / 12, col = Mn + (rem - row*12);
    (buf ? f1T : f0T)[(size_t)row*STR + col] = 0;
  }
}

// ---------------------------------------------------------------------------
// K1: fused convs + Q/K projection; 16 nodes per 256-block, 250 blocks
__global__ __launch_bounds__(256) void k_convqk(
    const in_t* __restrict__ x, const in_t* __restrict__ wsw, const in_t* __restrict__ wsb,
    const in_t* __restrict__ wlw, const in_t* __restrict__ wlb,
    const in_t* __restrict__ WQw, const in_t* __restrict__ WQb,
    const in_t* __restrict__ WKw, const in_t* __restrict__ WKb,
    float* __restrict__ f0, unsigned short* __restrict__ f0T,
    float* __restrict__ Q, float* __restrict__ Kt)
{
  __shared__ float sw[KC*65], lw[KC*65];
  __shared__ float sb[KC], lb[KC];
  __shared__ float xs[16*65];
  __shared__ float wq[HA*33], wk[HA*33];
  __shared__ float bq[HA], bk[HA];
  __shared__ float hsq[16][33];
  int tid = threadIdx.x;
  for (int idx = tid; idx < KC*Tn; idx += 256) {
    int k = idx >> 6, t = idx & 63;
    sw[k*65+t] = wsw[idx];
    lw[k*65+t] = 0.5f * wlw[k*32 + (t>>1)];
  }
  if (tid < KC) { sb[tid] = wsb[tid]; lb[tid] = wlb[tid]; }
  for (int idx = tid; idx < HA*32; idx += 256) {
    int a = idx >> 5, c = idx & 31;
    wq[a*33+c] = WQw[idx];
    wk[a*33+c] = WKw[idx];
  }
  if (tid < HA) { bq[tid] = WQb[tid]; bk[tid] = WKb[tid]; }
  int ng0 = blockIdx.x * 16;
  for (int idx = tid; idx < 16*Tn; idx += 256) {
    int t = idx >> 4, nl = idx & 15;
    int ng = ng0 + nl;
    int b = ng / Mn, m = ng - b*Mn;
    xs[nl*65 + t] = x[(size_t)b*Tn*Mn + (size_t)t*Mn + m];
  }
  __syncthreads();
  int nl = tid >> 4, k = tid & 15;
  int ng = ng0 + nl;
  int b = ng / Mn, m = ng - b*Mn;
  {
    float s = 0.f, l = 0.f;
    #pragma unroll
    for (int t = 0; t < Tn; ++t) {
      float xv = xs[nl*65+t];
      s += xv * sw[k*65+t];
      l += xv * lw[k*65+t];
    }
    float vs = fmaxf(s + sb[k], 0.f);
    float vl = fmaxf(l + lb[k], 0.f);
    size_t base = (size_t)b*Mn + m;
    f0[base*DF + k]       = vs; f0[base*DF + KC + k]  = vl;
    f0T[((size_t)b*DF + k)*STR + m]      = f2h(vs);
    f0T[((size_t)b*DF + KC + k)*STR + m] = f2h(vl);
    hsq[nl][k] = vs; hsq[nl][KC + k] = vl;
  }
  __syncthreads();
  // Q/K phase: 8 outputs per thread (4 Q + 4 K), e = tid&15
  int e = k;
  #pragma unroll
  for (int g = 0; g < 4; ++g) {
    int a = g*16 + e;
    float aq = bq[a], ak = bk[a];
    #pragma unroll
    for (int c = 0; c < 32; ++c) {
      float hv = hsq[nl][c];
      aq += hv * wq[a*33+c];
      ak += hv * wk[a*33+c];
    }
    Q[(size_t)ng*HA + a]  = aq;
    Kt[(size_t)ng*HA + a] = ak;
  }
}

// ---------------------------------------------------------------------------
// K3: split-K partial Gram
__global__ __launch_bounds__(256) void k_gram(
    const float* __restrict__ Kt, float* __restrict__ Gpart, float* __restrict__ Kpart)
{
  int split = blockIdx.x, b = blockIdx.y;
  int tid = threadIdx.x;
  __shared__ float L[64][HA];
  int m0 = split*63;
  int mend = min(m0 + 63, Mn);
  int p = tid & 63;
  int q0 = (tid >> 6) * 16;
  float acc[16];
  #pragma unroll
  for (int e = 0; e < 16; ++e) acc[e] = 0.f;
  for (int idx = tid; idx < 64*HA; idx += 256) {
    int r = idx >> 6, c = idx & 63;
    int m = m0 + r;
    L[r][c] = (m < mend) ? Kt[((size_t)b*Mn + m)*HA + c] : 0.f;
  }
  __syncthreads();
  float ks = 0.f;
  #pragma unroll 4
  for (int r = 0; r < 63; ++r) {
    float lp = L[r][p];
    if (tid < 64) ks += lp;
    #pragma unroll
    for (int e = 0; e < 16; ++e) acc[e] += lp * L[r][q0+e];
  }
  float* gp = Gpart + ((size_t)split*Bz + b)*HA*HA;
  #pragma unroll
  for (int e = 0; e < 16; ++e) gp[p*HA + q0 + e] = acc[e];
  if (tid < 64) Kpart[((size_t)split*Bz + b)*HA + tid] = ks;
}

// K3b: sum the GSPLIT partials once per batch
__global__ __launch_bounds__(256) void k_gfin(
    const float* __restrict__ Gpart, const float* __restrict__ Kpart,
    float* __restrict__ Gfull, float* __restrict__ Kfull)
{
  int b = blockIdx.x;
  int tid = threadIdx.x;
  for (int i = tid; i < HA*HA; i += 256) {
    float s = 0.f;
    #pragma unroll
    for (int sp = 0; sp < GSPLIT; ++sp) s += Gpart[((size_t)sp*Bz + b)*HA*HA + i];
    Gfull[(size_t)b*HA*HA + i] = s;
  }
  if (tid < HA) {
    float s = 0.f;
    #pragma unroll
    for (int sp = 0; sp < GSPLIT; ++sp) s += Kpart[((size_t)sp*Bz + b)*HA + tid];
    Kfull[b*HA + tid] = s;
  }
}

// ---------------------------------------------------------------------------
// K4: s-glob + h_L; wave-per-m (4 m per block), 1000 blocks
__global__ __launch_bounds__(256) void k_sglob(
    const float* __restrict__ Q, const float* __restrict__ Gfull, const float* __restrict__ Kfull,
    const in_t* __restrict__ degree, const in_t* __restrict__ tencw, const in_t* __restrict__ tencb,
    const in_t* __restrict__ sencw, const in_t* __restrict__ sencb,
    float* __restrict__ f0, unsigned short* __restrict__ f0T)
{
  __shared__ float Gs[HA*65];
  __shared__ float qs[4][HA];
  __shared__ float Ks[HA], tw[HR], tb[HR], sw2[HR], sb2[HR];
  int tid = threadIdx.x;
  int gid0 = blockIdx.x*4;
  int b = gid0 / Mn;
  for (int idx = tid; idx < HA*HA; idx += 256) {
    int p = idx >> 6, c = idx & 63;
    Gs[p*65+c] = Gfull[(size_t)b*HA*HA + idx];
  }
  for (int idx = tid; idx < 4*HA; idx += 256)
    qs[idx>>6][idx&63] = Q[(size_t)gid0*HA + idx];
  if (tid < HA) {
    Ks[tid] = Kfull[b*HA + tid];
    tw[tid] = tencw[tid]; tb[tid] = tencb[tid];
    sw2[tid] = sencw[tid]; sb2[tid] = sencb[tid];
  }
  __syncthreads();
  int w = tid >> 6, p = tid & 63;
  int gid = gid0 + w;
  int m = gid - b*Mn;
  float t = 0.f;
  #pragma unroll
  for (int c = 0; c < HA; ++c) t += Gs[p*65+c] * qs[w][c];
  float qpv = qs[w][p];
  float qq = qpv * t;
  float rs = qpv * Ks[p];
  #pragma unroll
  for (int off = 32; off; off >>= 1) {
    qq += __shfl_xor(qq, off, 64);
    rs += __shfl_xor(rs, off, 64);
  }
  float nrm = fmaxf(sqrtf(fmaxf(qq, 0.f)), 1e-12f);
  float s = rs / nrm;
  float dg = degree[m];
  float v1 = s*tw[p] + tb[p];
  float v2 = dg*sw2[p] + sb2[p];
  float* fp = f0 + (size_t)gid*DF;
  fp[32+p] = v1;
  fp[96+p] = v2;
  f0T[((size_t)b*DF + 32 + p)*STR + m] = f2h(v1);
  f0T[((size_t)b*DF + 96 + p)*STR + m] = f2h(v2);
}

// ---------------------------------------------------------------------------
// K5: GRU — fdot2 + LDS h exchange (b128 reads) + x in LDS; 8 seq/block, 500 blocks
__global__ __launch_bounds__(256) void k_gru(
    const in_t* __restrict__ x, const in_t* __restrict__ Wih, const in_t* __restrict__ Whh,
    const in_t* __restrict__ bih, const in_t* __restrict__ bhh, float* __restrict__ lh)
{
  __shared__ unsigned int h2[8][24];   // 16 used + pad to 96B stride (16B aligned)
  __shared__ float xs[Tn*8];
  int tid = threadIdx.x;
  int hid = tid & 31;
  int ls  = tid >> 5;
  int seq = blockIdx.x*8 + ls;
  int b = seq / Mn, m = seq - b*Mn;
  for (int idx = tid; idx < Tn*8; idx += 256) {
    int t = idx >> 3, s = idx & 7;
    int gs = blockIdx.x*8 + s;
    int bb = gs / Mn, mm = gs - bb*Mn;
    xs[idx] = x[(size_t)bb*Tn*Mn + (size_t)t*Mn + mm];
  }
  unsigned int wr2[16], wz2[16], wn2[16];
  #pragma unroll
  for (int p = 0; p < 16; ++p) {
    wr2[p] = pack2h(Whh[(size_t)hid*32 + 2*p],      Whh[(size_t)hid*32 + 2*p + 1]);
    wz2[p] = pack2h(Whh[(size_t)(32+hid)*32 + 2*p], Whh[(size_t)(32+hid)*32 + 2*p + 1]);
    wn2[p] = pack2h(Whh[(size_t)(64+hid)*32 + 2*p], Whh[(size_t)(64+hid)*32 + 2*p + 1]);
  }
  float wir = Wih[hid], wiz = Wih[32+hid], win = Wih[64+hid];
  float brc  = bih[hid]    + bhh[hid];
  float bzc  = bih[32+hid] + bhh[32+hid];
  float binc = bih[64+hid];
  float bhnc = bhh[64+hid];
  if (!(hid & 1)) h2[ls][hid>>1] = 0u;
  __syncthreads();
  float h = 0.f;
  for (int t = 0; t < Tn; ++t) {
    float xcur = xs[t*8 + ls];
    u32x4 hv0 = *reinterpret_cast<const u32x4*>(&h2[ls][0]);
    u32x4 hv1 = *reinterpret_cast<const u32x4*>(&h2[ls][4]);
    u32x4 hv2 = *reinterpret_cast<const u32x4*>(&h2[ls][8]);
    u32x4 hv3 = *reinterpret_cast<const u32x4*>(&h2[ls][12]);
    unsigned int hvv[16] = {hv0[0],hv0[1],hv0[2],hv0[3], hv1[0],hv1[1],hv1[2],hv1[3],
                            hv2[0],hv2[1],hv2[2],hv2[3], hv3[0],hv3[1],hv3[2],hv3[3]};
    float rg = 0.f, zg = 0.f, ng = 0.f;
    #pragma unroll
    for (int p = 0; p < 16; ++p) {
      h2v hp = __builtin_bit_cast(h2v, hvv[p]);
      rg = __builtin_amdgcn_fdot2(__builtin_bit_cast(h2v, wr2[p]), hp, rg, false);
      zg = __builtin_amdgcn_fdot2(__builtin_bit_cast(h2v, wz2[p]), hp, zg, false);
      ng = __builtin_amdgcn_fdot2(__builtin_bit_cast(h2v, wn2[p]), hp, ng, false);
    }
    float r = sigm(xcur*wir + brc + rg);
    float z = sigm(xcur*wiz + bzc + zg);
    float n = tanhfast(xcur*win + binc + r*(ng + bhnc));
    h = (1.f - z)*n + z*h;
    float hpart = __shfl_xor(h, 1, 64);
    unsigned int pk = (hid & 1) ? pack2h(hpart, h) : pack2h(h, hpart);
    if (!(hid & 1)) h2[ls][hid>>1] = pk;
  }
  lh[(size_t)seq*NHID + hid] = h;
}

// ---------------------------------------------------------------------------
// K6: A1/A2; thread = (gid, a); 8 gids x 32 a per block, 500 blocks
__global__ __launch_bounds__(256) void k_a1a2(
    const float* __restrict__ lh, const in_t* __restrict__ W1, const in_t* __restrict__ W2,
    float* __restrict__ A1, float* __restrict__ A2)
{
  __shared__ float w1[32*33], w2[32*33];
  __shared__ float hs[8][33];
  int tid = threadIdx.x;
  for (int idx = tid; idx < 1024; idx += 256) {
    int a = idx >> 5, c = idx & 31;
    w1[a*33+c] = W1[idx];
    w2[a*33+c] = W2[idx];
  }
  int gid0 = blockIdx.x * 8;
  for (int idx = tid; idx < 256; idx += 256)
    hs[idx>>5][idx&31] = lh[(size_t)gid0*32 + idx];
  __syncthreads();
  int g = tid >> 5, a = tid & 31;
  int gid = gid0 + g;
  float s1 = 0.f, s2 = 0.f;
  #pragma unroll
  for (int c = 0; c < 32; ++c) {
    float hv = hs[g][c];
    s1 += hv * w1[a*33+c];
    s2 += hv * w2[a*33+c];
  }
  A1[(size_t)gid*32 + a] = s1;
  A2[(size_t)gid*32 + a] = s2;
}

// ---------------------------------------------------------------------------
// K8: pair — 32x32 tile, 2x2 outputs/thread; grid (16,16,Bz)
__global__ __launch_bounds__(256) void k_pair(
    const float* __restrict__ A1, const float* __restrict__ A2, const in_t* __restrict__ Vv,
    const in_t* __restrict__ b1, const in_t* __restrict__ bv, float* __restrict__ aB)
{
  __shared__ float a1s[32][33], a2s[32][33], vs[32], b1s[32];
  int b = blockIdx.z;
  int i0 = blockIdx.y*32, j0 = blockIdx.x*32;
  int tid = threadIdx.x;
  if (tid < 32) { vs[tid] = Vv[tid]; b1s[tid] = b1[tid]; }
  {
    int r = tid >> 5, c = tid & 31;
    for (int rr = r; rr < 32; rr += 8) {
      int i = i0 + rr, j = j0 + rr;
      a1s[rr][c] = (i < Mn) ? A1[((size_t)b*Mn + i)*32 + c] : 0.f;
      a2s[rr][c] = (j < Mn) ? A2[((size_t)b*Mn + j)*32 + c] : 0.f;
    }
  }
  __syncthreads();
  int ti = tid >> 4, tj = tid & 15;
  float acc00 = 0.f, acc01 = 0.f, acc10 = 0.f, acc11 = 0.f;
  #pragma unroll
  for (int c = 0; c < 32; ++c) {
    float va0 = a1s[ti][c],      va1 = a1s[ti+16][c];
    float vb0 = a2s[tj][c],      vb1 = a2s[tj+16][c];
    float bb = b1s[c], vv = vs[c];
    acc00 += eluf(va0 + vb0 + bb) * vv;
    acc01 += eluf(va0 + vb1 + bb) * vv;
    acc10 += eluf(va1 + vb0 + bb) * vv;
    acc11 += eluf(va1 + vb1 + bb) * vv;
  }
  float bvv = bv[0];
  int i = i0 + ti, j = j0 + tj;
  if (i < Mn) {
    if (j < Mn)      aB[((size_t)b*Mn + i)*Mn + j]      = acc00 + bvv;
    if (j+16 < Mn)   aB[((size_t)b*Mn + i)*Mn + j + 16] = acc01 + bvv;
  }
  if (i+16 < Mn) {
    if (j < Mn)      aB[((size_t)b*Mn + i + 16)*Mn + j]      = acc10 + bvv;
    if (j+16 < Mn)   aB[((size_t)b*Mn + i + 16)*Mn + j + 16] = acc11 + bvv;
  }
}

// ---------------------------------------------------------------------------
// K9a: partial column sum-squares over row chunks; grid (4 jblk, 8 isplit, Bz)
__global__ __launch_bounds__(128) void k_cnorm(const float* __restrict__ aB, float* __restrict__ ssp)
{
  int jb = blockIdx.x, isp = blockIdx.y, b = blockIdx.z;
  int j = jb*128 + threadIdx.x;
  if (j >= Mn) return;
  int i0 = isp*63, iend = min(i0 + 63, Mn);
  const float* ap = aB + (size_t)b*Mn*Mn + j;
  float ss = 0.f;
  for (int i = i0; i < iend; ++i) { float v = ap[(size_t)i*Mn]; ss += v*v; }
  ssp[((size_t)isp*Bz + b)*Mn + j] = ss;
}

// K9b: finalize cinv
__global__ __launch_bounds__(256) void k_cfin(const float* __restrict__ ssp, float* __restrict__ cinv)
{
  int idx = blockIdx.x*256 + threadIdx.x;
  if (idx >= Bz*Mn) return;
  int b = idx / Mn, j = idx - b*Mn;
  float ss = 0.f;
  #pragma unroll
  for (int sp = 0; sp < 8; ++sp) ss += ssp[((size_t)sp*Bz + b)*Mn + j];
  cinv[idx] = 1.f / fmaxf(sqrtf(ss), 1e-12f);
}

// ---------------------------------------------------------------------------
// K9c: anB = fp16(aB * cinv), stride STR, pads zeroed; grid (Mn, Bz)
__global__ __launch_bounds__(256) void k_prepa(
    const float* __restrict__ aB, const float* __restrict__ cinv, unsigned short* __restrict__ anB)
{
  int b = blockIdx.y, i = blockIdx.x;
  const float* row = aB + ((size_t)b*Mn + i)*Mn;
  const float* civ = cinv + (size_t)b*Mn;
  unsigned short* orow = anB + ((size_t)b*Mn + i)*STR;
  for (int j = threadIdx.x; j < STR; j += 256)
    orow[j] = (j < Mn) ? f2h(row[j]*civ[j]) : (unsigned short)0;
}

// ---------------------------------------------------------------------------
// K10: c_gate GEMM fp16 MFMA; u32x4 staging; epilogue: dmat inline, adjb fp16
__global__ __launch_bounds__(512) void k_cgemm(
    const unsigned short* __restrict__ anB, const unsigned short* __restrict__ WbT,
    const in_t* __restrict__ wb, const in_t* __restrict__ adj_geo,
    const in_t* __restrict__ dgate, const in_t* __restrict__ degree,
    unsigned short* __restrict__ adjb)
{
  __shared__ unsigned short As[64*72], Bs[64*72];
  int b = blockIdx.z, i0 = blockIdx.y*64, j0 = blockIdx.x*64;
  int tid = threadIdx.x;
  int w = tid >> 6, lane = tid & 63, ln = lane & 15, lg = lane >> 4;
  int wm = (w >> 2)*32, wn = (w & 3)*16;
  int sr = tid >> 3, se = tid & 7;     // staging: row 0..63, chunk 0..7
  f32x4 acc[2];
  acc[0] = (f32x4)(0.f); acc[1] = (f32x4)(0.f);

  for (int k0 = 0; k0 < 512; k0 += 64) {
    {
      int i = i0 + sr, k = k0 + 8*se;
      u32x4 v = {0,0,0,0};
      if (i < Mn) v = *reinterpret_cast<const u32x4*>(&anB[((size_t)b*Mn + i)*STR + k]);
      *reinterpret_cast<u32x4*>(&As[sr*72 + 8*se]) = v;
      int j = j0 + sr;
      u32x4 vb = {0,0,0,0};
      if (j < Mn) vb = *reinterpret_cast<const u32x4*>(&WbT[(size_t)j*STR + k]);
      *reinterpret_cast<u32x4*>(&Bs[sr*72 + 8*se]) = vb;
    }
    __syncthreads();
    #pragma unroll
    for (int kk = 0; kk < 2; ++kk) {
      half8 a0 = *reinterpret_cast<const half8*>(&As[(wm + 0  + ln)*72 + kk*32 + lg*8]);
      half8 a1 = *reinterpret_cast<const half8*>(&As[(wm + 16 + ln)*72 + kk*32 + lg*8]);
      half8 b0 = *reinterpret_cast<const half8*>(&Bs[(wn + ln)*72 + kk*32 + lg*8]);
      acc[0] = MFMAH(a0, b0, acc[0], 0, 0, 0);
      acc[1] = MFMAH(a1, b0, acc[1], 0, 0, 0);
    }
    __syncthreads();
  }
  float wbv = wb[0];
  int j = j0 + wn + ln;
  if (j < Mn) {
    float degj = degree[j];
    #pragma unroll
    for (int mt = 0; mt < 2; ++mt)
      #pragma unroll
      for (int r = 0; r < 4; ++r) {
        int i = i0 + wm + mt*16 + lg*4 + r;
        if (i < Mn) {
          float cg = sigm(acc[mt][r] + wbv);
          float av = h2f(anB[((size_t)b*Mn + i)*STR + j]);
          float ag = adj_geo[(size_t)i*Mn + j];
          float dm = sigm(dgate[(size_t)i*Mn + j] * degree[i] * degj);
          float adjf = ag*cg + av*(1.f - cg) + dm*ag;
          adjb[((size_t)b*Mn + i)*STR + j] = f2h((adjf > 0.f) ? 1.f : adjf);
        }
      }
  }
}

// ---------------------------------------------------------------------------
// K11: laplace row-normalize (fp16 in, stride STR) -> fp16 lapB, pads zeroed
__global__ __launch_bounds__(256) void k_lap(const unsigned short* __restrict__ adjb, unsigned short* __restrict__ lapB)
{
  int b = blockIdx.y, i = blockIdx.x;
  const unsigned short* row = adjb + ((size_t)b*Mn + i)*STR;
  int tid = threadIdx.x;
  float s = 0.f;
  for (int j = tid; j < Mn; j += 256) s += h2f(row[j]);
  __shared__ float red[8];
  int lane = tid & 63, wv = tid >> 6;
  #pragma unroll
  for (int off = 32; off; off >>= 1) s += __shfl_down(s, off);
  if (lane == 0) red[wv] = s;
  __syncthreads();
  if (tid == 0) {
    float d = red[0] + red[1] + red[2] + red[3];
    red[4] = (d > 0.f) ? 1.f/d : 0.f;
  }
  __syncthreads();
  float inv = red[4];
  unsigned short* lrow = lapB + ((size_t)b*Mn + i)*STR;
  for (int j = tid; j < STR; j += 256)
    lrow[j] = (j < Mn) ? f2h(h2f(row[j])*inv) : (unsigned short)0;
}

// ---------------------------------------------------------------------------
// K12: spmm via fp16 MFMA, 32x32 tiles, u32x4 staging: grid (5, 16, Bz)
__global__ __launch_bounds__(256) void k_spmm(
    const unsigned short* __restrict__ lapB, const unsigned short* __restrict__ fT,
    unsigned short* __restrict__ tmpB)
{
  __shared__ unsigned short As[32*72], Bs[32*72];
  int b = blockIdx.z, i0 = blockIdx.y*32, j0 = blockIdx.x*32;
  int tid = threadIdx.x;
  int w = tid >> 6, lane = tid & 63, ln = lane & 15, lg = lane >> 4;
  int wm = (w >> 1)*16, wn = (w & 1)*16;
  int sr = tid >> 3, se = tid & 7;    // row 0..31, chunk 0..7
  f32x4 acc = (f32x4)(0.f);

  for (int k0 = 0; k0 < 512; k0 += 64) {
    {
      int i = i0 + sr, k = k0 + 8*se;
      u32x4 v = {0,0,0,0};
      if (i < Mn) v = *reinterpret_cast<const u32x4*>(&lapB[((size_t)b*Mn + i)*STR + k]);
      *reinterpret_cast<u32x4*>(&As[sr*72 + 8*se]) = v;
      int d = j0 + sr;
      u32x4 vb = *reinterpret_cast<const u32x4*>(&fT[((size_t)b*DF + d)*STR + k]);
      *reinterpret_cast<u32x4*>(&Bs[sr*72 + 8*se]) = vb;
    }
    __syncthreads();
    #pragma unroll
    for (int kk = 0; kk < 2; ++kk) {
      half8 a0 = *reinterpret_cast<const half8*>(&As[(wm + ln)*72 + kk*32 + lg*8]);
      half8 b0 = *reinterpret_cast<const half8*>(&Bs[(wn + ln)*72 + kk*32 + lg*8]);
      acc = MFMAH(a0, b0, acc, 0, 0, 0);
    }
    __syncthreads();
  }
  #pragma unroll
  for (int r = 0; r < 4; ++r) {
    int i = i0 + wm + lg*4 + r;
    int j = j0 + wn + ln;
    if (i < Mn)
      tmpB[((size_t)b*Mn + i)*DF + j] = f2h(acc[r]);
  }
}

// ---------------------------------------------------------------------------
// K13: dense 32x32 tiles, u32x4 staging, fp16 gnnT (k padded to 192): grid (5, 125)
__global__ __launch_bounds__(256) void k_dense(
    const unsigned short* __restrict__ tmpB, const unsigned short* __restrict__ gnnT,
    const in_t* __restrict__ bias,
    float* __restrict__ fout, unsigned short* __restrict__ foutT)
{
  __shared__ unsigned short As[32*72], Bs[32*72];
  __shared__ float bs[32];
  int i0 = blockIdx.y*32, j0 = blockIdx.x*32;
  int tid = threadIdx.x;
  if (tid < 32) bs[tid] = bias[j0 + tid];
  int w = tid >> 6, lane = tid & 63, ln = lane & 15, lg = lane >> 4;
  int wm = (w >> 1)*16, wn = (w & 1)*16;
  int sr = tid >> 3, se = tid & 7;
  f32x4 acc = (f32x4)(0.f);

  for (int k0 = 0; k0 < 192; k0 += 64) {
    {
      int i = i0 + sr, k = k0 + 8*se;
      u32x4 v = {0,0,0,0};
      if (k < DF) v = *reinterpret_cast<const u32x4*>(&tmpB[(size_t)i*DF + k]);
      *reinterpret_cast<u32x4*>(&As[sr*72 + 8*se]) = v;
      int j = j0 + sr;
      u32x4 vb = *reinterpret_cast<const u32x4*>(&gnnT[(size_t)j*192 + k]);
      *reinterpret_cast<u32x4*>(&Bs[sr*72 + 8*se]) = vb;
    }
    __syncthreads();
    #pragma unroll
    for (int kk = 0; kk < 2; ++kk) {
      half8 a0 = *reinterpret_cast<const half8*>(&As[(wm + ln)*72 + kk*32 + lg*8]);
      half8 b0 = *reinterpret_cast<const half8*>(&Bs[(wn + ln)*72 + kk*32 + lg*8]);
      acc = MFMAH(a0, b0, acc, 0, 0, 0);
    }
    __syncthreads();
  }
  #pragma unroll
  for (int r = 0; r < 4; ++r) {
    int i = i0 + wm + lg*4 + r;
    int jl = wn + ln;
    int j = j0 + jl;
    float val = eluf(acc[r] + bs[jl]);
    fout[(size_t)i*DF + j] = val;
    if (foutT) {
      int bb = i / Mn, mm = i - bb*Mn;
      foutT[((size_t)bb*DF + j)*STR + mm] = f2h(val);
    }
  }
}

// ---------------------------------------------------------------------------
// K14: output projection — one wave per output row, lanes over channels
__global__ __launch_bounds__(256) void k_out(
    const float* __restrict__ f0, const float* __restrict__ f1, const float* __restrict__ f2,
    const float* __restrict__ lh, const in_t* __restrict__ ow, const in_t* __restrict__ ob,
    float* __restrict__ outp)
{
  __shared__ float w[FINALC];
  int tid = threadIdx.x;
  for (int i = tid; i < FINALC; i += 256) w[i] = ow[i];
  __syncthreads();
  int lane = tid & 63;
  int gid = blockIdx.x*4 + (tid >> 6);
  const float* p0 = f0 + (size_t)gid*DF;
  const float* p1 = f1 + (size_t)gid*DF;
  const float* p2 = f2 + (size_t)gid*DF;
  const float* pl = lh + (size_t)gid*NHID;
  float s = 0.f;
  #pragma unroll
  for (int ch = 0; ch < 8; ++ch) {
    int ci = ch*64 + lane;
    float v;
    if (ci < DF)          v = p0[ci];
    else if (ci < 2*DF)   v = p1[ci - DF];
    else if (ci < 3*DF)   v = p2[ci - 2*DF];
    else                  v = pl[ci - 3*DF];
    s += v * w[ci];
  }
  #pragma unroll
  for (int off = 32; off; off >>= 1) s += __shfl_down(s, off, 64);
  if (lane == 0) outp[gid] = s + ob[0];
}

// ---------------------------------------------------------------------------
extern "C" void kernel_launch(void* const* d_in, const int* in_sizes, int n_in,
                              void* d_out, int out_size, void* d_ws, size_t ws_size,
                              hipStream_t stream)
{
  const in_t* x       = (const in_t*)d_in[0];
  const in_t* adj_geo = (const in_t*)d_in[1];
  const in_t* degree  = (const in_t*)d_in[2];
  const in_t* conv_s_w= (const in_t*)d_in[3];
  const in_t* conv_s_b= (const in_t*)d_in[4];
  const in_t* conv_l_w= (const in_t*)d_in[5];
  const in_t* conv_l_b= (const in_t*)d_in[6];
  const in_t* WQ_w    = (const in_t*)d_in[7];
  const in_t* WQ_b    = (const in_t*)d_in[8];
  const in_t* WK_w    = (const in_t*)d_in[9];
  const in_t* WK_b    = (const in_t*)d_in[10];
  const in_t* tenc_w  = (const in_t*)d_in[11];
  const in_t* tenc_b  = (const in_t*)d_in[12];
  const in_t* senc_w  = (const in_t*)d_in[13];
  const in_t* senc_b  = (const in_t*)d_in[14];
  const in_t* gru_Wih = (const in_t*)d_in[15];
  const in_t* gru_Whh = (const in_t*)d_in[16];
  const in_t* gru_bih = (const in_t*)d_in[17];
  const in_t* gru_bhh = (const in_t*)d_in[18];
  const in_t* Vv      = (const in_t*)d_in[19];
  const in_t* W1      = (const in_t*)d_in[20];
  const in_t* W2      = (const in_t*)d_in[21];
  const in_t* Wb      = (const in_t*)d_in[22];
  const in_t* bv      = (const in_t*)d_in[23];
  const in_t* b1      = (const in_t*)d_in[24];
  const in_t* wb      = (const in_t*)d_in[25];
  const in_t* d_gate  = (const in_t*)d_in[26];
  const in_t* gnn_w   = (const in_t*)d_in[27];
  const in_t* gnn_b   = (const in_t*)d_in[28];
  const in_t* out_w   = (const in_t*)d_in[29];
  const in_t* out_b   = (const in_t*)d_in[30];
  float* out = (float*)d_out;

  // workspace carve-up (float offsets)
  float* ws   = (float*)d_ws;
  float* Qb   = ws;                         // 256000
  float* Ktb  = ws + 256000;                // 256000
  float* lh   = ws + 512000;                // 128000
  float* A1   = ws + 640000;                // 128000
  float* A2   = ws + 768000;                // 128000
  float* aB   = ws + 896000;                // 2000000 f32 (lapB overlays after prepa)
  float* cinv = ws + 2896000;               // 4000
  float* R    = ws + 2900000;               // 1024000 (transients, then fp16 adjb)
  float* f0   = ws + 3924000;               // 640000
  float* f1   = ws + 4564000;               // 640000
  float* f2   = ws + 5204000;               // 640000
  unsigned short* f0T  = (unsigned short*)(ws + 5844000);  // 8*160*512 halfs
  unsigned short* tmpB = (unsigned short*)(ws + 6171680);  // 4000*160 halfs
  unsigned short* f1T  = (unsigned short*)(ws + 6491680);  // 8*160*512 halfs
  unsigned short* anB  = (unsigned short*)(ws + 6819360);  // 8*500*512 halfs
  unsigned short* WbT  = (unsigned short*)(ws + 7843360);  // 500*512 halfs
  unsigned short* gnnT = (unsigned short*)(ws + 7971360);  // 2*160*192 halfs
  unsigned short* lapB = (unsigned short*)aB;              // 8*500*512 halfs overlay
  unsigned short* adjb = (unsigned short*)R;               // 8*500*512 halfs
  float* Gpart = R;                    // 262144 (dead before cgemm)
  float* Kpart = R + 262144;           // 4096
  float* ssp   = R + 266240;           // 32000
  float* Gfull = R + 298240;           // 32768
  float* Kfull = R + 331008;           // 512

  k_prep<<<dim3(424), 256, 0, stream>>>(Wb, WbT, gnn_w, gnnT, f0T, f1T);
  k_convqk<<<dim3(250), 256, 0, stream>>>(x, conv_s_w, conv_s_b, conv_l_w, conv_l_b,
                                          WQ_w, WQ_b, WK_w, WK_b, f0, f0T, Qb, Ktb);
  k_gram<<<dim3(GSPLIT, Bz), 256, 0, stream>>>(Ktb, Gpart, Kpart);
  k_gfin<<<dim3(Bz), 256, 0, stream>>>(Gpart, Kpart, Gfull, Kfull);
  k_sglob<<<dim3(1000), 256, 0, stream>>>(Qb, Gfull, Kfull, degree, tenc_w, tenc_b, senc_w, senc_b, f0, f0T);
  k_gru<<<dim3(500), 256, 0, stream>>>(x, gru_Wih, gru_Whh, gru_bih, gru_bhh, lh);
  k_a1a2<<<dim3(500), 256, 0, stream>>>(lh, W1, W2, A1, A2);
  k_pair<<<dim3(16, 16, Bz), 256, 0, stream>>>(A1, A2, Vv, b1, bv, aB);
  k_cnorm<<<dim3(4, 8, Bz), 128, 0, stream>>>(aB, ssp);
  k_cfin<<<dim3(16), 256, 0, stream>>>(ssp, cinv);
  k_prepa<<<dim3(Mn, Bz), 256, 0, stream>>>(aB, cinv, anB);
  k_cgemm<<<dim3(8, 8, Bz), 512, 0, stream>>>(anB, WbT, wb, adj_geo, d_gate, degree, adjb);
  k_lap<<<dim3(Mn, Bz), 256, 0, stream>>>(adjb, lapB);
  // GNN layer 0
  k_spmm<<<dim3(5, 16, Bz), 256, 0, stream>>>(lapB, f0T, tmpB);
  k_dense<<<dim3(5, 125), 256, 0, stream>>>(tmpB, gnnT, gnn_b, f1, f1T);
  // GNN layer 1
  k_spmm<<<dim3(5, 16, Bz), 256, 0, stream>>>(lapB, f1T, tmpB);
  k_dense<<<dim3(5, 125), 256, 0, stream>>>(tmpB, gnnT + (size_t)DF*192, gnn_b + DF, f2, (unsigned short*)nullptr);
  k_out<<<dim3(1000), 256, 0, stream>>>(f0, f1, f2, lh, out_w, out_b, out);
}

// Round 19
// 176.233 us; speedup vs baseline: 1.0408x; 1.0408x over previous
//
#include <hip/hip_runtime.h>
#include <hip/hip_bf16.h>

// Problem constants
#define Bz 8
#define Tn 64
#define Mn 500
#define KC 16
#define HA 64
#define HR 64
#define NHID 32
#define DF 160
#define FINALC 512
#define GSPLIT 8
#define STR 512            // padded row stride (halfwords) for Mn-inner fp16 mats

typedef float in_t;   // reference dtypes are all float32
typedef __attribute__((ext_vector_type(8))) _Float16 half8;
typedef __attribute__((ext_vector_type(2))) _Float16 h2v;
typedef __attribute__((ext_vector_type(4))) float f32x4;
typedef __attribute__((ext_vector_type(4))) unsigned int u32x4;
#define MFMAH __builtin_amdgcn_mfma_f32_16x16x32_f16

__device__ __forceinline__ float sigm(float x){ return 1.0f/(1.0f+__expf(-x)); }
__device__ __forceinline__ float tanhfast(float x){ float e=__expf(2.0f*x); return 1.0f-2.0f/(e+1.0f); }
__device__ __forceinline__ float eluf(float x){ return x>0.0f? x : (__expf(x)-1.0f); }
__device__ __forceinline__ unsigned short f2h(float f){
  _Float16 h = (_Float16)f;
  return *reinterpret_cast<unsigned short*>(&h);
}
__device__ __forceinline__ float h2f(unsigned short u){
  _Float16 h = *reinterpret_cast<_Float16*>(&u);
  return (float)h;
}
__device__ __forceinline__ unsigned int pack2h(float a, float b){
  return (unsigned int)f2h(a) | ((unsigned int)f2h(b) << 16);
}

// ---------------------------------------------------------------------------
// K0: fused prep — blocks [0,64) WbT transpose; [64,304) gnnT; [304,424) zpad
__global__ __launch_bounds__(256) void k_prep(
    const in_t* __restrict__ Wb, unsigned short* __restrict__ WbT,
    const in_t* __restrict__ gw, unsigned short* __restrict__ gnnT,
    unsigned short* __restrict__ f0T, unsigned short* __restrict__ f1T)
{
  int blk = blockIdx.x;
  int tid = threadIdx.x;
  if (blk < 64) {
    __shared__ unsigned short ts[64][72];
    int k0 = (blk >> 3)*64, j0 = (blk & 7)*64;
    for (int idx = tid; idx < 4096; idx += 256) {
      int r = idx >> 6, c = idx & 63;
      int k = k0 + r, j = j0 + c;
      ts[r][c] = (k < Mn && j < Mn) ? f2h(Wb[(size_t)k*Mn + j]) : (unsigned short)0;
    }
    __syncthreads();
    for (int idx = tid; idx < 4096; idx += 256) {
      int jr = idx >> 6, kc = idx & 63;
      int j = j0 + jr, k = k0 + kc;
      if (j < Mn) WbT[(size_t)j*STR + k] = ts[kc][jr];
    }
  } else if (blk < 304) {
    int idx = (blk - 64)*256 + tid;     // 61440 = 2*160*192 exact
    int l = idx / (DF*192);
    int rem = idx - l*(DF*192);
    int j = rem / 192, k = rem - j*192;
    gnnT[((size_t)l*DF + j)*192 + k] =
        (k < DF) ? f2h(gw[(size_t)l*DF*DF + (size_t)k*DF + j]) : (unsigned short)0;
  } else {
    int idx = (blk - 304)*256 + tid;    // 30720 = 2*8*160*12 exact
    int buf = idx / (Bz*DF*12);
    int rem = idx - buf*(Bz*DF*12);
    int row = rem / 12, col = Mn + (rem - row*12);
    (buf ? f1T : f0T)[(size_t)row*STR + col] = 0;
  }
}

// ---------------------------------------------------------------------------
// K1: fused convs + Q/K projection; 16 nodes per 256-block, 250 blocks
__global__ __launch_bounds__(256) void k_convqk(
    const in_t* __restrict__ x, const in_t* __restrict__ wsw, const in_t* __restrict__ wsb,
    const in_t* __restrict__ wlw, const in_t* __restrict__ wlb,
    const in_t* __restrict__ WQw, const in_t* __restrict__ WQb,
    const in_t* __restrict__ WKw, const in_t* __restrict__ WKb,
    float* __restrict__ f0, unsigned short* __restrict__ f0T,
    float* __restrict__ Q, float* __restrict__ Kt)
{
  __shared__ float sw[KC*65], lw[KC*65];
  __shared__ float sb[KC], lb[KC];
  __shared__ float xs[16*65];
  __shared__ float wq[HA*33], wk[HA*33];
  __shared__ float bq[HA], bk[HA];
  __shared__ float hsq[16][33];
  int tid = threadIdx.x;
  for (int idx = tid; idx < KC*Tn; idx += 256) {
    int k = idx >> 6, t = idx & 63;
    sw[k*65+t] = wsw[idx];
    lw[k*65+t] = 0.5f * wlw[k*32 + (t>>1)];
  }
  if (tid < KC) { sb[tid] = wsb[tid]; lb[tid] = wlb[tid]; }
  for (int idx = tid; idx < HA*32; idx += 256) {
    int a = idx >> 5, c = idx & 31;
    wq[a*33+c] = WQw[idx];
    wk[a*33+c] = WKw[idx];
  }
  if (tid < HA) { bq[tid] = WQb[tid]; bk[tid] = WKb[tid]; }
  int ng0 = blockIdx.x * 16;
  for (int idx = tid; idx < 16*Tn; idx += 256) {
    int t = idx >> 4, nl = idx & 15;
    int ng = ng0 + nl;
    int b = ng / Mn, m = ng - b*Mn;
    xs[nl*65 + t] = x[(size_t)b*Tn*Mn + (size_t)t*Mn + m];
  }
  __syncthreads();
  int nl = tid >> 4, k = tid & 15;
  int ng = ng0 + nl;
  int b = ng / Mn, m = ng - b*Mn;
  {
    float s = 0.f, l = 0.f;
    #pragma unroll
    for (int t = 0; t < Tn; ++t) {
      float xv = xs[nl*65+t];
      s += xv * sw[k*65+t];
      l += xv * lw[k*65+t];
    }
    float vs = fmaxf(s + sb[k], 0.f);
    float vl = fmaxf(l + lb[k], 0.f);
    size_t base = (size_t)b*Mn + m;
    f0[base*DF + k]       = vs; f0[base*DF + KC + k]  = vl;
    f0T[((size_t)b*DF + k)*STR + m]      = f2h(vs);
    f0T[((size_t)b*DF + KC + k)*STR + m] = f2h(vl);
    hsq[nl][k] = vs; hsq[nl][KC + k] = vl;
  }
  __syncthreads();
  // Q/K phase: 8 outputs per thread (4 Q + 4 K), e = tid&15
  int e = k;
  #pragma unroll
  for (int g = 0; g < 4; ++g) {
    int a = g*16 + e;
    float aq = bq[a], ak = bk[a];
    #pragma unroll
    for (int c = 0; c < 32; ++c) {
      float hv = hsq[nl][c];
      aq += hv * wq[a*33+c];
      ak += hv * wk[a*33+c];
    }
    Q[(size_t)ng*HA + a]  = aq;
    Kt[(size_t)ng*HA + a] = ak;
  }
}

// ---------------------------------------------------------------------------
// K3: split-K partial Gram
__global__ __launch_bounds__(256) void k_gram(
    const float* __restrict__ Kt, float* __restrict__ Gpart, float* __restrict__ Kpart)
{
  int split = blockIdx.x, b = blockIdx.y;
  int tid = threadIdx.x;
  __shared__ float L[64][HA];
  int m0 = split*63;
  int mend = min(m0 + 63, Mn);
  int p = tid & 63;
  int q0 = (tid >> 6) * 16;
  float acc[16];
  #pragma unroll
  for (int e = 0; e < 16; ++e) acc[e] = 0.f;
  for (int idx = tid; idx < 64*HA; idx += 256) {
    int r = idx >> 6, c = idx & 63;
    int m = m0 + r;
    L[r][c] = (m < mend) ? Kt[((size_t)b*Mn + m)*HA + c] : 0.f;
  }
  __syncthreads();
  float ks = 0.f;
  #pragma unroll 4
  for (int r = 0; r < 63; ++r) {
    float lp = L[r][p];
    if (tid < 64) ks += lp;
    #pragma unroll
    for (int e = 0; e < 16; ++e) acc[e] += lp * L[r][q0+e];
  }
  float* gp = Gpart + ((size_t)split*Bz + b)*HA*HA;
  #pragma unroll
  for (int e = 0; e < 16; ++e) gp[p*HA + q0 + e] = acc[e];
  if (tid < 64) Kpart[((size_t)split*Bz + b)*HA + tid] = ks;
}

// K3b: sum the GSPLIT partials once per batch
__global__ __launch_bounds__(256) void k_gfin(
    const float* __restrict__ Gpart, const float* __restrict__ Kpart,
    float* __restrict__ Gfull, float* __restrict__ Kfull)
{
  int b = blockIdx.x;
  int tid = threadIdx.x;
  for (int i = tid; i < HA*HA; i += 256) {
    float s = 0.f;
    #pragma unroll
    for (int sp = 0; sp < GSPLIT; ++sp) s += Gpart[((size_t)sp*Bz + b)*HA*HA + i];
    Gfull[(size_t)b*HA*HA + i] = s;
  }
  if (tid < HA) {
    float s = 0.f;
    #pragma unroll
    for (int sp = 0; sp < GSPLIT; ++sp) s += Kpart[((size_t)sp*Bz + b)*HA + tid];
    Kfull[b*HA + tid] = s;
  }
}

// ---------------------------------------------------------------------------
// K4: s-glob + h_L; wave-per-m (4 m per block), 1000 blocks
__global__ __launch_bounds__(256) void k_sglob(
    const float* __restrict__ Q, const float* __restrict__ Gfull, const float* __restrict__ Kfull,
    const in_t* __restrict__ degree, const in_t* __restrict__ tencw, const in_t* __restrict__ tencb,
    const in_t* __restrict__ sencw, const in_t* __restrict__ sencb,
    float* __restrict__ f0, unsigned short* __restrict__ f0T)
{
  __shared__ float Gs[HA*65];
  __shared__ float qs[4][HA];
  __shared__ float Ks[HA], tw[HR], tb[HR], sw2[HR], sb2[HR];
  int tid = threadIdx.x;
  int gid0 = blockIdx.x*4;
  int b = gid0 / Mn;
  for (int idx = tid; idx < HA*HA; idx += 256) {
    int p = idx >> 6, c = idx & 63;
    Gs[p*65+c] = Gfull[(size_t)b*HA*HA + idx];
  }
  for (int idx = tid; idx < 4*HA; idx += 256)
    qs[idx>>6][idx&63] = Q[(size_t)gid0*HA + idx];
  if (tid < HA) {
    Ks[tid] = Kfull[b*HA + tid];
    tw[tid] = tencw[tid]; tb[tid] = tencb[tid];
    sw2[tid] = sencw[tid]; sb2[tid] = sencb[tid];
  }
  __syncthreads();
  int w = tid >> 6, p = tid & 63;
  int gid = gid0 + w;
  int m = gid - b*Mn;
  float t = 0.f;
  #pragma unroll
  for (int c = 0; c < HA; ++c) t += Gs[p*65+c] * qs[w][c];
  float qpv = qs[w][p];
  float qq = qpv * t;
  float rs = qpv * Ks[p];
  #pragma unroll
  for (int off = 32; off; off >>= 1) {
    qq += __shfl_xor(qq, off, 64);
    rs += __shfl_xor(rs, off, 64);
  }
  float nrm = fmaxf(sqrtf(fmaxf(qq, 0.f)), 1e-12f);
  float s = rs / nrm;
  float dg = degree[m];
  float v1 = s*tw[p] + tb[p];
  float v2 = dg*sw2[p] + sb2[p];
  float* fp = f0 + (size_t)gid*DF;
  fp[32+p] = v1;
  fp[96+p] = v2;
  f0T[((size_t)b*DF + 32 + p)*STR + m] = f2h(v1);
  f0T[((size_t)b*DF + 96 + p)*STR + m] = f2h(v2);
}

// ---------------------------------------------------------------------------
// K5: GRU — fdot2 + LDS h exchange (b128 reads) + x in LDS; 8 seq/block, 500 blocks
__global__ __launch_bounds__(256) void k_gru(
    const in_t* __restrict__ x, const in_t* __restrict__ Wih, const in_t* __restrict__ Whh,
    const in_t* __restrict__ bih, const in_t* __restrict__ bhh, float* __restrict__ lh)
{
  __shared__ unsigned int h2[8][24];   // 16 used + pad to 96B stride (16B aligned)
  __shared__ float xs[Tn*8];
  int tid = threadIdx.x;
  int hid = tid & 31;
  int ls  = tid >> 5;
  int seq = blockIdx.x*8 + ls;
  int b = seq / Mn, m = seq - b*Mn;
  for (int idx = tid; idx < Tn*8; idx += 256) {
    int t = idx >> 3, s = idx & 7;
    int gs = blockIdx.x*8 + s;
    int bb = gs / Mn, mm = gs - bb*Mn;
    xs[idx] = x[(size_t)bb*Tn*Mn + (size_t)t*Mn + mm];
  }
  unsigned int wr2[16], wz2[16], wn2[16];
  #pragma unroll
  for (int p = 0; p < 16; ++p) {
    wr2[p] = pack2h(Whh[(size_t)hid*32 + 2*p],      Whh[(size_t)hid*32 + 2*p + 1]);
    wz2[p] = pack2h(Whh[(size_t)(32+hid)*32 + 2*p], Whh[(size_t)(32+hid)*32 + 2*p + 1]);
    wn2[p] = pack2h(Whh[(size_t)(64+hid)*32 + 2*p], Whh[(size_t)(64+hid)*32 + 2*p + 1]);
  }
  float wir = Wih[hid], wiz = Wih[32+hid], win = Wih[64+hid];
  float brc  = bih[hid]    + bhh[hid];
  float bzc  = bih[32+hid] + bhh[32+hid];
  float binc = bih[64+hid];
  float bhnc = bhh[64+hid];
  if (!(hid & 1)) h2[ls][hid>>1] = 0u;
  __syncthreads();
  float h = 0.f;
  for (int t = 0; t < Tn; ++t) {
    float xcur = xs[t*8 + ls];
    u32x4 hv0 = *reinterpret_cast<const u32x4*>(&h2[ls][0]);
    u32x4 hv1 = *reinterpret_cast<const u32x4*>(&h2[ls][4]);
    u32x4 hv2 = *reinterpret_cast<const u32x4*>(&h2[ls][8]);
    u32x4 hv3 = *reinterpret_cast<const u32x4*>(&h2[ls][12]);
    unsigned int hvv[16] = {hv0[0],hv0[1],hv0[2],hv0[3], hv1[0],hv1[1],hv1[2],hv1[3],
                            hv2[0],hv2[1],hv2[2],hv2[3], hv3[0],hv3[1],hv3[2],hv3[3]};
    float rg = 0.f, zg = 0.f, ng = 0.f;
    #pragma unroll
    for (int p = 0; p < 16; ++p) {
      h2v hp = __builtin_bit_cast(h2v, hvv[p]);
      rg = __builtin_amdgcn_fdot2(__builtin_bit_cast(h2v, wr2[p]), hp, rg, false);
      zg = __builtin_amdgcn_fdot2(__builtin_bit_cast(h2v, wz2[p]), hp, zg, false);
      ng = __builtin_amdgcn_fdot2(__builtin_bit_cast(h2v, wn2[p]), hp, ng, false);
    }
    float r = sigm(xcur*wir + brc + rg);
    float z = sigm(xcur*wiz + bzc + zg);
    float n = tanhfast(xcur*win + binc + r*(ng + bhnc));
    h = (1.f - z)*n + z*h;
    float hpart = __shfl_xor(h, 1, 64);
    unsigned int pk = (hid & 1) ? pack2h(hpart, h) : pack2h(h, hpart);
    if (!(hid & 1)) h2[ls][hid>>1] = pk;
  }
  lh[(size_t)seq*NHID + hid] = h;
}

// ---------------------------------------------------------------------------
// K6: A1/A2; thread = (gid, a); 8 gids x 32 a per block, 500 blocks
__global__ __launch_bounds__(256) void k_a1a2(
    const float* __restrict__ lh, const in_t* __restrict__ W1, const in_t* __restrict__ W2,
    float* __restrict__ A1, float* __restrict__ A2)
{
  __shared__ float w1[32*33], w2[32*33];
  __shared__ float hs[8][33];
  int tid = threadIdx.x;
  for (int idx = tid; idx < 1024; idx += 256) {
    int a = idx >> 5, c = idx & 31;
    w1[a*33+c] = W1[idx];
    w2[a*33+c] = W2[idx];
  }
  int gid0 = blockIdx.x * 8;
  for (int idx = tid; idx < 256; idx += 256)
    hs[idx>>5][idx&31] = lh[(size_t)gid0*32 + idx];
  __syncthreads();
  int g = tid >> 5, a = tid & 31;
  int gid = gid0 + g;
  float s1 = 0.f, s2 = 0.f;
  #pragma unroll
  for (int c = 0; c < 32; ++c) {
    float hv = hs[g][c];
    s1 += hv * w1[a*33+c];
    s2 += hv * w2[a*33+c];
  }
  A1[(size_t)gid*32 + a] = s1;
  A2[(size_t)gid*32 + a] = s2;
}

// ---------------------------------------------------------------------------
// K8: a[b,i,j] = V . elu(A1_i + A2_j + b1) + bv   (f32 — sign feeds binarize)
__global__ __launch_bounds__(256) void k_pair(
    const float* __restrict__ A1, const float* __restrict__ A2, const in_t* __restrict__ Vv,
    const in_t* __restrict__ b1, const in_t* __restrict__ bv, float* __restrict__ aB)
{
  __shared__ float a1s[16][33], a2s[16][33], vs[32], b1s[32];
  int b = blockIdx.z;
  int i0 = blockIdx.y*16, j0 = blockIdx.x*16;
  int tid = threadIdx.x;
  if (tid < 32) { vs[tid] = Vv[tid]; b1s[tid] = b1[tid]; }
  {
    int r = tid >> 5, c = tid & 31;
    for (int rr = r; rr < 16; rr += 8) {
      int i = i0 + rr, j = j0 + rr;
      a1s[rr][c] = (i < Mn) ? A1[((size_t)b*Mn + i)*32 + c] : 0.f;
      a2s[rr][c] = (j < Mn) ? A2[((size_t)b*Mn + j)*32 + c] : 0.f;
    }
  }
  __syncthreads();
  int ti = tid >> 4, tj = tid & 15;
  int i = i0 + ti, j = j0 + tj;
  if (i >= Mn || j >= Mn) return;
  float acc = 0.f;
  #pragma unroll
  for (int c = 0; c < 32; ++c) {
    float u = a1s[ti][c] + a2s[tj][c] + b1s[c];
    acc += eluf(u) * vs[c];
  }
  aB[((size_t)b*Mn + i)*Mn + j] = acc + bv[0];
}

// ---------------------------------------------------------------------------
// K9a: partial column sum-squares over row chunks; grid (4 jblk, 8 isplit, Bz)
__global__ __launch_bounds__(128) void k_cnorm(const float* __restrict__ aB, float* __restrict__ ssp)
{
  int jb = blockIdx.x, isp = blockIdx.y, b = blockIdx.z;
  int j = jb*128 + threadIdx.x;
  if (j >= Mn) return;
  int i0 = isp*63, iend = min(i0 + 63, Mn);
  const float* ap = aB + (size_t)b*Mn*Mn + j;
  float ss = 0.f;
  for (int i = i0; i < iend; ++i) { float v = ap[(size_t)i*Mn]; ss += v*v; }
  ssp[((size_t)isp*Bz + b)*Mn + j] = ss;
}

// K9b: finalize cinv
__global__ __launch_bounds__(256) void k_cfin(const float* __restrict__ ssp, float* __restrict__ cinv)
{
  int idx = blockIdx.x*256 + threadIdx.x;
  if (idx >= Bz*Mn) return;
  int b = idx / Mn, j = idx - b*Mn;
  float ss = 0.f;
  #pragma unroll
  for (int sp = 0; sp < 8; ++sp) ss += ssp[((size_t)sp*Bz + b)*Mn + j];
  cinv[idx] = 1.f / fmaxf(sqrtf(ss), 1e-12f);
}

// ---------------------------------------------------------------------------
// K9c: anB = fp16(aB * cinv), stride STR, pads zeroed; grid (Mn, Bz)
__global__ __launch_bounds__(256) void k_prepa(
    const float* __restrict__ aB, const float* __restrict__ cinv, unsigned short* __restrict__ anB)
{
  int b = blockIdx.y, i = blockIdx.x;
  const float* row = aB + ((size_t)b*Mn + i)*Mn;
  const float* civ = cinv + (size_t)b*Mn;
  unsigned short* orow = anB + ((size_t)b*Mn + i)*STR;
  for (int j = threadIdx.x; j < STR; j += 256)
    orow[j] = (j < Mn) ? f2h(row[j]*civ[j]) : (unsigned short)0;
}

// ---------------------------------------------------------------------------
// K10: c_gate GEMM fp16 MFMA; u32x4 staging; epilogue: dmat inline, adjb fp16
__global__ __launch_bounds__(512) void k_cgemm(
    const unsigned short* __restrict__ anB, const unsigned short* __restrict__ WbT,
    const in_t* __restrict__ wb, const in_t* __restrict__ adj_geo,
    const in_t* __restrict__ dgate, const in_t* __restrict__ degree,
    unsigned short* __restrict__ adjb)
{
  __shared__ unsigned short As[64*72], Bs[64*72];
  int b = blockIdx.z, i0 = blockIdx.y*64, j0 = blockIdx.x*64;
  int tid = threadIdx.x;
  int w = tid >> 6, lane = tid & 63, ln = lane & 15, lg = lane >> 4;
  int wm = (w >> 2)*32, wn = (w & 3)*16;
  int sr = tid >> 3, se = tid & 7;     // staging: row 0..63, chunk 0..7
  f32x4 acc[2];
  acc[0] = (f32x4)(0.f); acc[1] = (f32x4)(0.f);

  for (int k0 = 0; k0 < 512; k0 += 64) {
    {
      int i = i0 + sr, k = k0 + 8*se;
      u32x4 v = {0,0,0,0};
      if (i < Mn) v = *reinterpret_cast<const u32x4*>(&anB[((size_t)b*Mn + i)*STR + k]);
      *reinterpret_cast<u32x4*>(&As[sr*72 + 8*se]) = v;
      int j = j0 + sr;
      u32x4 vb = {0,0,0,0};
      if (j < Mn) vb = *reinterpret_cast<const u32x4*>(&WbT[(size_t)j*STR + k]);
      *reinterpret_cast<u32x4*>(&Bs[sr*72 + 8*se]) = vb;
    }
    __syncthreads();
    #pragma unroll
    for (int kk = 0; kk < 2; ++kk) {
      half8 a0 = *reinterpret_cast<const half8*>(&As[(wm + 0  + ln)*72 + kk*32 + lg*8]);
      half8 a1 = *reinterpret_cast<const half8*>(&As[(wm + 16 + ln)*72 + kk*32 + lg*8]);
      half8 b0 = *reinterpret_cast<const half8*>(&Bs[(wn + ln)*72 + kk*32 + lg*8]);
      acc[0] = MFMAH(a0, b0, acc[0], 0, 0, 0);
      acc[1] = MFMAH(a1, b0, acc[1], 0, 0, 0);
    }
    __syncthreads();
  }
  float wbv = wb[0];
  int j = j0 + wn + ln;
  if (j < Mn) {
    float degj = degree[j];
    #pragma unroll
    for (int mt = 0; mt < 2; ++mt)
      #pragma unroll
      for (int r = 0; r < 4; ++r) {
        int i = i0 + wm + mt*16 + lg*4 + r;
        if (i < Mn) {
          float cg = sigm(acc[mt][r] + wbv);
          float av = h2f(anB[((size_t)b*Mn + i)*STR + j]);
          float ag = adj_geo[(size_t)i*Mn + j];
          float dm = sigm(dgate[(size_t)i*Mn + j] * degree[i] * degj);
          float adjf = ag*cg + av*(1.f - cg) + dm*ag;
          adjb[((size_t)b*Mn + i)*STR + j] = f2h((adjf > 0.f) ? 1.f : adjf);
        }
      }
  }
}

// ---------------------------------------------------------------------------
// K11: laplace row-normalize (fp16 in, stride STR) -> fp16 lapB, pads zeroed
__global__ __launch_bounds__(256) void k_lap(const unsigned short* __restrict__ adjb, unsigned short* __restrict__ lapB)
{
  int b = blockIdx.y, i = blockIdx.x;
  const unsigned short* row = adjb + ((size_t)b*Mn + i)*STR;
  int tid = threadIdx.x;
  float s = 0.f;
  for (int j = tid; j < Mn; j += 256) s += h2f(row[j]);
  __shared__ float red[8];
  int lane = tid & 63, wv = tid >> 6;
  #pragma unroll
  for (int off = 32; off; off >>= 1) s += __shfl_down(s, off);
  if (lane == 0) red[wv] = s;
  __syncthreads();
  if (tid == 0) {
    float d = red[0] + red[1] + red[2] + red[3];
    red[4] = (d > 0.f) ? 1.f/d : 0.f;
  }
  __syncthreads();
  float inv = red[4];
  unsigned short* lrow = lapB + ((size_t)b*Mn + i)*STR;
  for (int j = tid; j < STR; j += 256)
    lrow[j] = (j < Mn) ? f2h(h2f(row[j])*inv) : (unsigned short)0;
}

// ---------------------------------------------------------------------------
// K12: spmm via fp16 MFMA, 32x32 tiles, u32x4 staging: grid (5, 16, Bz)
__global__ __launch_bounds__(256) void k_spmm(
    const unsigned short* __restrict__ lapB, const unsigned short* __restrict__ fT,
    unsigned short* __restrict__ tmpB)
{
  __shared__ unsigned short As[32*72], Bs[32*72];
  int b = blockIdx.z, i0 = blockIdx.y*32, j0 = blockIdx.x*32;
  int tid = threadIdx.x;
  int w = tid >> 6, lane = tid & 63, ln = lane & 15, lg = lane >> 4;
  int wm = (w >> 1)*16, wn = (w & 1)*16;
  int sr = tid >> 3, se = tid & 7;    // row 0..31, chunk 0..7
  f32x4 acc = (f32x4)(0.f);

  for (int k0 = 0; k0 < 512; k0 += 64) {
    {
      int i = i0 + sr, k = k0 + 8*se;
      u32x4 v = {0,0,0,0};
      if (i < Mn) v = *reinterpret_cast<const u32x4*>(&lapB[((size_t)b*Mn + i)*STR + k]);
      *reinterpret_cast<u32x4*>(&As[sr*72 + 8*se]) = v;
      int d = j0 + sr;
      u32x4 vb = *reinterpret_cast<const u32x4*>(&fT[((size_t)b*DF + d)*STR + k]);
      *reinterpret_cast<u32x4*>(&Bs[sr*72 + 8*se]) = vb;
    }
    __syncthreads();
    #pragma unroll
    for (int kk = 0; kk < 2; ++kk) {
      half8 a0 = *reinterpret_cast<const half8*>(&As[(wm + ln)*72 + kk*32 + lg*8]);
      half8 b0 = *reinterpret_cast<const half8*>(&Bs[(wn + ln)*72 + kk*32 + lg*8]);
      acc = MFMAH(a0, b0, acc, 0, 0, 0);
    }
    __syncthreads();
  }
  #pragma unroll
  for (int r = 0; r < 4; ++r) {
    int i = i0 + wm + lg*4 + r;
    int j = j0 + wn + ln;
    if (i < Mn)
      tmpB[((size_t)b*Mn + i)*DF + j] = f2h(acc[r]);
  }
}

// ---------------------------------------------------------------------------
// K13: dense 32x32 tiles, u32x4 staging, fp16 gnnT (k padded to 192): grid (5, 125)
__global__ __launch_bounds__(256) void k_dense(
    const unsigned short* __restrict__ tmpB, const unsigned short* __restrict__ gnnT,
    const in_t* __restrict__ bias,
    float* __restrict__ fout, unsigned short* __restrict__ foutT)
{
  __shared__ unsigned short As[32*72], Bs[32*72];
  __shared__ float bs[32];
  int i0 = blockIdx.y*32, j0 = blockIdx.x*32;
  int tid = threadIdx.x;
  if (tid < 32) bs[tid] = bias[j0 + tid];
  int w = tid >> 6, lane = tid & 63, ln = lane & 15, lg = lane >> 4;
  int wm = (w >> 1)*16, wn = (w & 1)*16;
  int sr = tid >> 3, se = tid & 7;
  f32x4 acc = (f32x4)(0.f);

  for (int k0 = 0; k0 < 192; k0 += 64) {
    {
      int i = i0 + sr, k = k0 + 8*se;
      u32x4 v = {0,0,0,0};
      if (k < DF) v = *reinterpret_cast<const u32x4*>(&tmpB[(size_t)i*DF + k]);
      *reinterpret_cast<u32x4*>(&As[sr*72 + 8*se]) = v;
      int j = j0 + sr;
      u32x4 vb = *reinterpret_cast<const u32x4*>(&gnnT[(size_t)j*192 + k]);
      *reinterpret_cast<u32x4*>(&Bs[sr*72 + 8*se]) = vb;
    }
    __syncthreads();
    #pragma unroll
    for (int kk = 0; kk < 2; ++kk) {
      half8 a0 = *reinterpret_cast<const half8*>(&As[(wm + ln)*72 + kk*32 + lg*8]);
      half8 b0 = *reinterpret_cast<const half8*>(&Bs[(wn + ln)*72 + kk*32 + lg*8]);
      acc = MFMAH(a0, b0, acc, 0, 0, 0);
    }
    __syncthreads();
  }
  #pragma unroll
  for (int r = 0; r < 4; ++r) {
    int i = i0 + wm + lg*4 + r;
    int jl = wn + ln;
    int j = j0 + jl;
    float val = eluf(acc[r] + bs[jl]);
    fout[(size_t)i*DF + j] = val;
    if (foutT) {
      int bb = i / Mn, mm = i - bb*Mn;
      foutT[((size_t)bb*DF + j)*STR + mm] = f2h(val);
    }
  }
}

// ---------------------------------------------------------------------------
// K14: output projection — one wave per output row, lanes over channels
__global__ __launch_bounds__(256) void k_out(
    const float* __restrict__ f0, const float* __restrict__ f1, const float* __restrict__ f2,
    const float* __restrict__ lh, const in_t* __restrict__ ow, const in_t* __restrict__ ob,
    float* __restrict__ outp)
{
  __shared__ float w[FINALC];
  int tid = threadIdx.x;
  for (int i = tid; i < FINALC; i += 256) w[i] = ow[i];
  __syncthreads();
  int lane = tid & 63;
  int gid = blockIdx.x*4 + (tid >> 6);
  const float* p0 = f0 + (size_t)gid*DF;
  const float* p1 = f1 + (size_t)gid*DF;
  const float* p2 = f2 + (size_t)gid*DF;
  const float* pl = lh + (size_t)gid*NHID;
  float s = 0.f;
  #pragma unroll
  for (int ch = 0; ch < 8; ++ch) {
    int ci = ch*64 + lane;
    float v;
    if (ci < DF)          v = p0[ci];
    else if (ci < 2*DF)   v = p1[ci - DF];
    else if (ci < 3*DF)   v = p2[ci - 2*DF];
    else                  v = pl[ci - 3*DF];
    s += v * w[ci];
  }
  #pragma unroll
  for (int off = 32; off; off >>= 1) s += __shfl_down(s, off, 64);
  if (lane == 0) outp[gid] = s + ob[0];
}

// ---------------------------------------------------------------------------
extern "C" void kernel_launch(void* const* d_in, const int* in_sizes, int n_in,
                              void* d_out, int out_size, void* d_ws, size_t ws_size,
                              hipStream_t stream)
{
  const in_t* x       = (const in_t*)d_in[0];
  const in_t* adj_geo = (const in_t*)d_in[1];
  const in_t* degree  = (const in_t*)d_in[2];
  const in_t* conv_s_w= (const in_t*)d_in[3];
  const in_t* conv_s_b= (const in_t*)d_in[4];
  const in_t* conv_l_w= (const in_t*)d_in[5];
  const in_t* conv_l_b= (const in_t*)d_in[6];
  const in_t* WQ_w    = (const in_t*)d_in[7];
  const in_t* WQ_b    = (const in_t*)d_in[8];
  const in_t* WK_w    = (const in_t*)d_in[9];
  const in_t* WK_b    = (const in_t*)d_in[10];
  const in_t* tenc_w  = (const in_t*)d_in[11];
  const in_t* tenc_b  = (const in_t*)d_in[12];
  const in_t* senc_w  = (const in_t*)d_in[13];
  const in_t* senc_b  = (const in_t*)d_in[14];
  const in_t* gru_Wih = (const in_t*)d_in[15];
  const in_t* gru_Whh = (const in_t*)d_in[16];
  const in_t* gru_bih = (const in_t*)d_in[17];
  const in_t* gru_bhh = (const in_t*)d_in[18];
  const in_t* Vv      = (const in_t*)d_in[19];
  const in_t* W1      = (const in_t*)d_in[20];
  const in_t* W2      = (const in_t*)d_in[21];
  const in_t* Wb      = (const in_t*)d_in[22];
  const in_t* bv      = (const in_t*)d_in[23];
  const in_t* b1      = (const in_t*)d_in[24];
  const in_t* wb      = (const in_t*)d_in[25];
  const in_t* d_gate  = (const in_t*)d_in[26];
  const in_t* gnn_w   = (const in_t*)d_in[27];
  const in_t* gnn_b   = (const in_t*)d_in[28];
  const in_t* out_w   = (const in_t*)d_in[29];
  const in_t* out_b   = (const in_t*)d_in[30];
  float* out = (float*)d_out;

  // workspace carve-up (float offsets)
  float* ws   = (float*)d_ws;
  float* Qb   = ws;                         // 256000
  float* Ktb  = ws + 256000;                // 256000
  float* lh   = ws + 512000;                // 128000
  float* A1   = ws + 640000;                // 128000
  float* A2   = ws + 768000;                // 128000
  float* aB   = ws + 896000;                // 2000000 f32 (lapB overlays after prepa)
  float* cinv = ws + 2896000;               // 4000
  float* R    = ws + 2900000;               // 1024000 (transients, then fp16 adjb)
  float* f0   = ws + 3924000;               // 640000
  float* f1   = ws + 4564000;               // 640000
  float* f2   = ws + 5204000;               // 640000
  unsigned short* f0T  = (unsigned short*)(ws + 5844000);  // 8*160*512 halfs
  unsigned short* tmpB = (unsigned short*)(ws + 6171680);  // 4000*160 halfs
  unsigned short* f1T  = (unsigned short*)(ws + 6491680);  // 8*160*512 halfs
  unsigned short* anB  = (unsigned short*)(ws + 6819360);  // 8*500*512 halfs
  unsigned short* WbT  = (unsigned short*)(ws + 7843360);  // 500*512 halfs
  unsigned short* gnnT = (unsigned short*)(ws + 7971360);  // 2*160*192 halfs
  unsigned short* lapB = (unsigned short*)aB;              // 8*500*512 halfs overlay
  unsigned short* adjb = (unsigned short*)R;               // 8*500*512 halfs
  float* Gpart = R;                    // 262144 (dead before cgemm)
  float* Kpart = R + 262144;           // 4096
  float* ssp   = R + 266240;           // 32000
  float* Gfull = R + 298240;           // 32768
  float* Kfull = R + 331008;           // 512

  k_prep<<<dim3(424), 256, 0, stream>>>(Wb, WbT, gnn_w, gnnT, f0T, f1T);
  k_convqk<<<dim3(250), 256, 0, stream>>>(x, conv_s_w, conv_s_b, conv_l_w, conv_l_b,
                                          WQ_w, WQ_b, WK_w, WK_b, f0, f0T, Qb, Ktb);
  k_gram<<<dim3(GSPLIT, Bz), 256, 0, stream>>>(Ktb, Gpart, Kpart);
  k_gfin<<<dim3(Bz), 256, 0, stream>>>(Gpart, Kpart, Gfull, Kfull);
  k_sglob<<<dim3(1000), 256, 0, stream>>>(Qb, Gfull, Kfull, degree, tenc_w, tenc_b, senc_w, senc_b, f0, f0T);
  k_gru<<<dim3(500), 256, 0, stream>>>(x, gru_Wih, gru_Whh, gru_bih, gru_bhh, lh);
  k_a1a2<<<dim3(500), 256, 0, stream>>>(lh, W1, W2, A1, A2);
  k_pair<<<dim3(32, 32, Bz), 256, 0, stream>>>(A1, A2, Vv, b1, bv, aB);
  k_cnorm<<<dim3(4, 8, Bz), 128, 0, stream>>>(aB, ssp);
  k_cfin<<<dim3(16), 256, 0, stream>>>(ssp, cinv);
  k_prepa<<<dim3(Mn, Bz), 256, 0, stream>>>(aB, cinv, anB);
  k_cgemm<<<dim3(8, 8, Bz), 512, 0, stream>>>(anB, WbT, wb, adj_geo, d_gate, degree, adjb);
  k_lap<<<dim3(Mn, Bz), 256, 0, stream>>>(adjb, lapB);
  // GNN layer 0
  k_spmm<<<dim3(5, 16, Bz), 256, 0, stream>>>(lapB, f0T, tmpB);
  k_dense<<<dim3(5, 125), 256, 0, stream>>>(tmpB, gnnT, gnn_b, f1, f1T);
  // GNN layer 1
  k_spmm<<<dim3(5, 16, Bz), 256, 0, stream>>>(lapB, f1T, tmpB);
  k_dense<<<dim3(5, 125), 256, 0, stream>>>(tmpB, gnnT + (size_t)DF*192, gnn_b + DF, f2, (unsigned short*)nullptr);
  k_out<<<dim3(1000), 256, 0, stream>>>(f0, f1, f2, lh, out_w, out_b, out);
}